// Round 2
// baseline (1088.384 us; speedup 1.0000x reference)
//
#include <hip/hip_runtime.h>

// Problem constants: B=2048, N=62 (pad 64), C_IN=512, L=3 layers, H=8, O=64.

using f32x4  = __attribute__((ext_vector_type(4)))  float;
using f32x16 = __attribute__((ext_vector_type(16))) float;
using s16x8  = __attribute__((ext_vector_type(8)))  short;

__device__ __forceinline__ unsigned short f2bf(float f){
  unsigned int u = __builtin_bit_cast(unsigned int, f);
  u += 0x7fffu + ((u >> 16) & 1u);              // RNE
  return (unsigned short)(u >> 16);
}
__device__ __forceinline__ float bf2f(unsigned short h){
  unsigned int u = ((unsigned int)h) << 16;
  return __builtin_bit_cast(float, u);
}
__device__ __forceinline__ f32x4 zf4(){ f32x4 v; v[0]=0.f; v[1]=0.f; v[2]=0.f; v[3]=0.f; return v; }

__device__ __forceinline__ void async16(const void* g, void* l){
  __builtin_amdgcn_global_load_lds((const __attribute__((address_space(1))) unsigned int*)g,
                                   (__attribute__((address_space(3))) unsigned int*)l,
                                   16, 0, 0);
}

__device__ __forceinline__ f32x16 mfma32(s16x8 a, s16x8 b, f32x16 c){
  return __builtin_amdgcn_mfma_f32_32x32x16_bf16(a, b, c, 0, 0, 0);
}
__device__ __forceinline__ f32x4 mfma16(s16x8 a, s16x8 b, f32x4 c){
  return __builtin_amdgcn_mfma_f32_16x16x32_bf16(a, b, c, 0, 0, 0);
}

// ---------------- K0: adjacency powers, A_hat (bf16, zero-padded 64x64), d_neg ----------------
__global__ void k_prep_adj(const float* __restrict__ L,
                           unsigned short* __restrict__ ahat,  // [3][64][64] bf16
                           float* __restrict__ dneg)           // [3][64] f32
{
  __shared__ float Ls[62*62];
  __shared__ float A2s[62*62];
  const int tid = threadIdx.x;
  for (int i = tid; i < 62*62; i += 256) Ls[i] = L[i];
  __syncthreads();
  for (int i = tid; i < 62*62; i += 256){
    const int n = i / 62, m = i % 62;
    float s = 0.f;
    for (int k = 0; k < 62; ++k) s += Ls[n*62 + k] * Ls[k*62 + m];
    A2s[i] = s;
  }
  __syncthreads();
  for (int i = tid; i < 3*64*64; i += 256){
    const int l = i >> 12, r = i & 4095, n = r >> 6, m = r & 63;
    float v = 0.f;
    if (n < 62 && m < 62){
      float base = 0.f;
      if (l == 0) base = (n == m) ? 1.f : 0.f;
      else if (l == 1) base = Ls[n*62 + m];
      else base = A2s[n*62 + m];
      v = base + ((n == m) ? 1.f : 0.f);          // A_hat = A + I
    }
    ahat[i] = f2bf(v);
  }
  for (int i = tid; i < 3*64; i += 256){
    const int l = i >> 6, n = i & 63;
    float D = 0.f;
    if (n < 62){
      if (l == 0) D = 1.f;
      else {
        const float* src = (l == 1) ? Ls : A2s;
        for (int m = 0; m < 62; ++m) D += src[n*62 + m];
      }
    }
    dneg[i] = (D == 0.f) ? 0.f : 1.f / D;
  }
}

// ---------------- K1: combined weight transpose + bf16, LDS-tiled (coalesced both sides) ----
// WC[lh][n 0..127][c 0..511]: n<64 -> Wa col n (n>=62 zero); n>=64 -> W col n-64.
// grid: 24 lh x 8 c-tiles = 192 blocks x 256 thr
__global__ void k_prep_w(const float* __restrict__ Wa, const float* __restrict__ W,
                         unsigned short* __restrict__ WC)
{
  __shared__ float t0[64*65];
  __shared__ float t1[64*65];
  const int lh = blockIdx.x >> 3;
  const int c0 = (blockIdx.x & 7) * 64;
  for (int i = threadIdx.x; i < 64*64; i += 256){
    const int cc = i >> 6, n = i & 63;          // consecutive tid -> consecutive n (coalesced src)
    t0[n*65 + cc] = (n < 62) ? Wa[((size_t)lh*512 + c0 + cc)*62 + n] : 0.f;
    t1[n*65 + cc] = W[((size_t)lh*512 + c0 + cc)*64 + n];
  }
  __syncthreads();
  for (int i = threadIdx.x; i < 64*64; i += 256){
    const int n = i >> 6, cc = i & 63;          // consecutive tid -> consecutive c (coalesced dst)
    WC[((size_t)lh*128 + n)*512 + c0 + cc]      = f2bf(t0[n*65 + cc]);
    WC[((size_t)lh*128 + 64 + n)*512 + c0 + cc] = f2bf(t1[n*65 + cc]);
  }
}

// ---------------- main fused kernel: one block per batch element b ----------------
#define LP 72   // padded LDS leading dim (halfs) for the small-GEMM tiles

// Stage one K=64 chunk (128 cols x 64 k, bf16) of WC[lh] into an LDS buffer.
// LDS row n holds its 8 16B-blocks XOR-swizzled: block kb stored at kb^(n&7).
// Dest is wave-uniform base + lane*16 (global_load_lds requirement); the
// swizzle is applied on the per-lane SOURCE address (gather side).
__device__ __forceinline__ void stage_chunk(const unsigned short* __restrict__ wcb, int kc,
                                            unsigned short* dst, int wv, int lane)
{
  const int l3 = lane >> 3, kb0 = lane & 7;
  #pragma unroll
  for (int t = 0; t < 4; ++t){
    const int n  = wv*32 + t*8 + l3;
    const int kb = kb0 ^ (n & 7);
    async16(wcb + (size_t)n*512 + kc*64 + kb*8,
            dst + wv*2048 + t*512 + lane*8);
  }
}

__global__ __launch_bounds__(256, 2)
void k_main(const float* __restrict__ x,
            const unsigned short* __restrict__ WC,
            const unsigned short* __restrict__ ahat,
            const float* __restrict__ dneg,
            float* __restrict__ out)
{
  __shared__ __align__(16) unsigned short s_chunk[2][8192]; // 2 bufs x 128 rows x 64 k bf16
  __shared__ __align__(16) unsigned short s_a[64*LP];       // logits -> softmax a  [n][m]
  __shared__ __align__(16) unsigned short s_xwT[64*LP];     // xW^T   [o][m']
  __shared__ __align__(16) unsigned short s_axwT[64*LP];    // axW^T  [o][m]
  __shared__ __align__(16) float s_dneg[192];
  __shared__ __align__(16) float s_red[256];
  __shared__ __align__(16) float s_red2[256];

  const int tid  = threadIdx.x;
  const int wv   = tid >> 6;      // wave 0..3
  const int lane = tid & 63;
  const int q    = lane >> 4;     // 16x16 quad
  const int m15  = lane & 15;
  const int l31  = lane & 31;     // 32x32 col
  const int lh5  = lane >> 5;     // 32x32 k-half
  const int wr   = wv >> 1;       // dual-GEMM row group (rows 32*wr..)
  const int wc   = wv & 1;        // dual-GEMM col group (cols 32*wc..)
  const int b    = blockIdx.x;
  const int r0   = 16*wv + 4*q;   // 16x16 C/D row base (small GEMMs)

  if (tid < 192) s_dneg[tid] = dneg[tid];

  // prefetch chunk 0 of lh=0 into buf0 (async, drained by prologue barrier)
  stage_chunk(WC, 0, &s_chunk[0][0], wv, lane);

  // Persistent A-fragments (32x32x16 layout): row m = 32*wr + l31,
  // afr[i] holds k = i*16 + 8*lh5 + j, j=0..7.  128 VGPRs.
  s16x8 afr[32];
  {
    const int row = 32*wr + l31;
    if (row < 62){
      const float* xp = x + ((size_t)b*62 + row)*512 + 8*lh5;
      #pragma unroll
      for (int i = 0; i < 32; ++i){
        const f32x4 f0 = *(const f32x4*)(xp + i*16);
        const f32x4 f1 = *(const f32x4*)(xp + i*16 + 4);
        s16x8 t;
        t[0]=(short)f2bf(f0[0]); t[1]=(short)f2bf(f0[1]); t[2]=(short)f2bf(f0[2]); t[3]=(short)f2bf(f0[3]);
        t[4]=(short)f2bf(f1[0]); t[5]=(short)f2bf(f1[1]); t[6]=(short)f2bf(f1[2]); t[7]=(short)f2bf(f1[3]);
        afr[i] = t;
      }
    } else {
      #pragma unroll
      for (int i = 0; i < 32; ++i){
        s16x8 t; t[0]=0;t[1]=0;t[2]=0;t[3]=0;t[4]=0;t[5]=0;t[6]=0;t[7]=0; afr[i] = t;
      }
    }
  }
  __syncthreads();   // publishes buf0 + s_dneg

  // B-frag LDS addressing (constant per thread)
  const int nA = wc*32 + l31;       // Wa-half row in chunk
  const int nX = nA + 64;           // W-half row in chunk
  const int n7 = nA & 7;

  #pragma unroll 1
  for (int h = 0; h < 8; ++h){
    f32x4 out_acc[4];
    #pragma unroll
    for (int ct = 0; ct < 4; ++ct) out_acc[ct] = zf4();

    #pragma unroll 1
    for (int l = 0; l < 3; ++l){
      const int lh = l*8 + h;
      int ln = l + 1, hn = h;
      if (ln == 3){ ln = 0; hn = (h + 1) & 7; }
      const int lh_next = ln*8 + hn;
      const unsigned short* wcb  = WC + (size_t)lh*65536;
      const unsigned short* wcbn = WC + (size_t)lh_next*65536;

      // ---- fused dual GEMM over K=512: [logits | xW] = x @ [Wa | W], 32x32x16 ----
      f32x16 accL, accX;
      #pragma unroll
      for (int i = 0; i < 16; ++i){ accL[i] = 0.f; accX[i] = 0.f; }

      #pragma unroll
      for (int ck = 0; ck < 8; ++ck){
        if (ck < 7) stage_chunk(wcb, ck+1, &s_chunk[(ck+1)&1][0], wv, lane); // prefetch
        const unsigned short* sc = &s_chunk[ck&1][0];
        #pragma unroll
        for (int ks = 0; ks < 4; ++ks){
          const s16x8 a  = afr[ck*4 + ks];
          const int   kb = 2*ks + lh5;
          const s16x8 bL = *(const s16x8*)(sc + nA*64 + ((kb ^ n7) * 8));
          const s16x8 bX = *(const s16x8*)(sc + nX*64 + ((kb ^ n7) * 8));
          accL = mfma32(a, bL, accL);
          accX = mfma32(a, bX, accX);
        }
        __syncthreads();  // publishes buf[(ck+1)&1]; drain overlapped with this chunk's MFMAs
      }

      // prefetch next lh's chunk 0 into buf0 (in flight across the softmax phase)
      stage_chunk(wcbn, 0, &s_chunk[0][0], wv, lane);

      // ---- epilogue (32x32 C/D: col=l31, row=(reg&3)+8*(reg>>2)+4*lh5) ----
      #pragma unroll
      for (int g = 0; g < 4; ++g){
        const f32x4 dn = *(const f32x4*)(&s_dneg[l*64 + 32*wr + 8*g + 4*lh5]);
        #pragma unroll
        for (int rr = 0; rr < 4; ++rr){
          const int row = 8*g + 4*lh5 + rr;
          const int n   = 32*wr + row;
          float v = accL[4*g + rr] * dn[rr];
          v = (v > 0.f) ? v : 0.01f*v;
          if (n >= 62) v = -1e30f;                 // exclude pad rows from softmax
          s_a[n*LP + 32*wc + l31]   = f2bf(v);
          s_xwT[(32*wc + l31)*LP + n] = f2bf(accX[4*g + rr]);  // xwT[o][m']
        }
      }
      __syncthreads();   // (A)

      // ---- axW = A_hat @ xW  (16x16x32; A-frags from global, L2-hot) ----
      f32x4 accA[4];
      #pragma unroll
      for (int ct = 0; ct < 4; ++ct) accA[ct] = zf4();
      #pragma unroll
      for (int ks = 0; ks < 2; ++ks){
        const s16x8 aA = *(const s16x8*)(ahat + (size_t)(l*64 + 16*wv + m15)*64 + ks*32 + q*8);
        #pragma unroll
        for (int ct = 0; ct < 4; ++ct){
          const s16x8 bA = *(const s16x8*)(&s_xwT[(16*ct + m15)*LP + ks*32 + q*8]);
          accA[ct] = mfma16(aA, bA, accA[ct]);
        }
      }
      #pragma unroll
      for (int ct = 0; ct < 4; ++ct){
        #pragma unroll
        for (int r = 0; r < 4; ++r)
          s_axwT[(16*ct + m15)*LP + (r0 + r)] = f2bf(accA[ct][r]);  // axwT[o][m]
      }

      // ---- softmax over n: thread owns col=lane, rows 16*wv..16*wv+15 ----
      float vsm[16];
      float mp = -3.0e38f;
      #pragma unroll
      for (int i = 0; i < 16; ++i){
        vsm[i] = bf2f(s_a[(16*wv + i)*LP + lane]);
        mp = fmaxf(mp, vsm[i]);
      }
      s_red[wv*64 + lane] = mp;
      __syncthreads();   // (B)
      const float mc = fmaxf(fmaxf(s_red[lane], s_red[64 + lane]),
                             fmaxf(s_red[128 + lane], s_red[192 + lane]));
      float ev[16]; float sp = 0.f;
      #pragma unroll
      for (int i = 0; i < 16; ++i){ ev[i] = __expf(vsm[i] - mc); sp += ev[i]; }
      s_red2[wv*64 + lane] = sp;
      __syncthreads();   // (C)
      const float sc2 = s_red2[lane] + s_red2[64 + lane] + s_red2[128 + lane] + s_red2[192 + lane];
      const float inv = 1.0f / sc2;
      #pragma unroll
      for (int i = 0; i < 16; ++i)
        s_a[(16*wv + i)*LP + lane] = f2bf(ev[i] * inv);
      __syncthreads();   // (D)

      // ---- o2 = a @ axW ; relu ; accumulate over layers (16x16x32) ----
      f32x4 accO[4];
      #pragma unroll
      for (int ct = 0; ct < 4; ++ct) accO[ct] = zf4();
      #pragma unroll
      for (int ks = 0; ks < 2; ++ks){
        const s16x8 aO = *(const s16x8*)(&s_a[(16*wv + m15)*LP + ks*32 + q*8]);
        #pragma unroll
        for (int ct = 0; ct < 4; ++ct){
          const s16x8 bO = *(const s16x8*)(&s_axwT[(16*ct + m15)*LP + ks*32 + q*8]);
          accO[ct] = mfma16(aO, bO, accO[ct]);
        }
      }
      #pragma unroll
      for (int ct = 0; ct < 4; ++ct){
        #pragma unroll
        for (int r = 0; r < 4; ++r)
          out_acc[ct][r] += fmaxf(accO[ct][r], 0.f);
      }
    } // l

    // ---- write this head's 64-wide output slice (final relu no-op on sum of relus) ----
    #pragma unroll
    for (int ct = 0; ct < 4; ++ct){
      const int col = h*64 + 16*ct + m15;
      #pragma unroll
      for (int r = 0; r < 4; ++r){
        const int n = r0 + r;
        if (n < 62)
          out[((size_t)b*62 + n)*512 + col] = fmaxf(out_acc[ct][r], 0.f);
      }
    }
  } // h
}

extern "C" void kernel_launch(void* const* d_in, const int* in_sizes, int n_in,
                              void* d_out, int out_size, void* d_ws, size_t ws_size,
                              hipStream_t stream)
{
  const float* x  = (const float*)d_in[0];   // (2048, 62, 512)
  const float* L  = (const float*)d_in[1];   // (62, 62)
  const float* Wa = (const float*)d_in[2];   // (3, 8, 512, 62)
  const float* W  = (const float*)d_in[3];   // (3, 8, 512, 64)
  float* out = (float*)d_out;                // (2048, 62, 512)

  char* ws = (char*)d_ws;
  unsigned short* ws_ahat = (unsigned short*)(ws);          // 24576 B
  float*          ws_dneg = (float*)(ws + 24576);           // 768 B (pad to 1024)
  unsigned short* ws_WC   = (unsigned short*)(ws + 25600);  // 24*128*512*2 = 3145728 B

  k_prep_adj<<<1, 256, 0, stream>>>(L, ws_ahat, ws_dneg);
  k_prep_w<<<192, 256, 0, stream>>>(Wa, W, ws_WC);
  k_main<<<2048, 256, 0, stream>>>(x, ws_WC, ws_ahat, ws_dneg, out);
}